// Round 6
// baseline (566.182 us; speedup 1.0000x reference)
//
#include <hip/hip_runtime.h>

#define NSEG 512
#define VSPLIT 64
#define HSPLIT 16
#define CHUNK 131072

typedef __attribute__((ext_vector_type(8))) short short8;
typedef __attribute__((ext_vector_type(4))) float floatx4;
typedef __attribute__((ext_vector_type(2))) float floatx2;

// ws layout (bytes), all 16B-aligned. total ~68.7 MB
#define WS_H      0u          // short [CHUNK][256] h chunk (bf16)
#define WS_RSMU   67108864u   // floatx2 [CHUNK]  (mu*rs, rs)
#define WS_WAT    68157440u   // short [256][32]  WA^T
#define WS_WBT2   68173824u   // short [256][64]  WB^T (K pad 48->64)
#define WS_W2GA   68206592u   // short [256][256] (gA*Wback)^T
#define WS_W2GB   68337664u   // short [256][256] (gB*Wback)^T
#define WS_C1A    68468736u   // float[8][256] partials
#define WS_C2A    68476928u
#define WS_C1B    68485120u
#define WS_C2B    68493312u
#define WS_C1AF   68501504u   // float[256] finals
#define WS_C2AF   68502528u
#define WS_C1BF   68503552u
#define WS_C2BF   68504576u
#define WS_INVA   68505600u   // float[32]
#define WS_INVB   68505728u   // float[48]
#define WS_VPART  68505920u   // float [VSPLIT][NSEG]
#define WS_CPART  68637056u   // float [HSPLIT][NSEG]
// end 68669824

__device__ __forceinline__ short f2bf(float f) {  // RNE
  unsigned u = __builtin_bit_cast(unsigned, f);
  u += 0x7FFFu + ((u >> 16) & 1u);
  return (short)(u >> 16);
}
__device__ __forceinline__ short f2bf_tr(float f) {  // truncate (1 inst)
  return (short)(__builtin_bit_cast(unsigned, f) >> 16);
}

__global__ void prep_kernel(const float* __restrict__ WA, const float* __restrict__ WB,
                            const float* __restrict__ Wback,
                            const float* __restrict__ gA, const float* __restrict__ betaA,
                            const float* __restrict__ gB, const float* __restrict__ betaB,
                            const float* __restrict__ bback,
                            const float* __restrict__ sA, const float* __restrict__ sB,
                            char* __restrict__ ws) {
  short* waT  = (short*)(ws + WS_WAT);
  short* wbT2 = (short*)(ws + WS_WBT2);
  short* w2gA = (short*)(ws + WS_W2GA);
  short* w2gB = (short*)(ws + WS_W2GB);
  int tid = blockIdx.x * blockDim.x + threadIdx.x;
  int stride = gridDim.x * blockDim.x;
  for (int i = tid; i < 32*256; i += stride) {          // WA[k][n] -> waT[n][k]
    int k = i >> 8, n = i & 255;
    waT[n*32 + k] = f2bf(WA[i]);
  }
  for (int i = tid; i < 256*64; i += stride) {          // WB[k][n] -> wbT2[n][k], pad K
    int n = i >> 6, k = i & 63;
    wbT2[i] = (k < 48) ? f2bf(WB[k*256 + n]) : (short)0;
  }
  for (int i = tid; i < 256*256; i += stride) {         // (g*Wback)[k][n] -> [n][k]
    int k = i >> 8, n = i & 255;
    float w = Wback[i];
    w2gA[n*256 + k] = f2bf(gA[k] * w);
    w2gB[n*256 + k] = f2bf(gB[k] * w);
  }
  if (blockIdx.x < 8) {                                  // c1/c2 partials, no atomics
    int kc = blockIdx.x, n = threadIdx.x;
    float a1 = 0.f, a2 = 0.f, b1 = 0.f, b2 = 0.f;
    for (int k = kc*32; k < kc*32 + 32; k++) {
      float w = Wback[k*256 + n];
      a1 += gA[k] * w;  a2 += betaA[k] * w;
      b1 += gB[k] * w;  b2 += betaB[k] * w;
    }
    float bb = (kc == 0) ? bback[n] : 0.0f;
    ((float*)(ws + WS_C1A))[kc*256 + n] = a1;
    ((float*)(ws + WS_C2A))[kc*256 + n] = a2 + bb;
    ((float*)(ws + WS_C1B))[kc*256 + n] = b1;
    ((float*)(ws + WS_C2B))[kc*256 + n] = b2 + bb;
  }
  if (tid < 32) ((float*)(ws + WS_INVA))[tid] = 1.0f / sA[tid];
  if (tid < 48) ((float*)(ws + WS_INVB))[tid] = 1.0f / sB[tid];
  float* vz = (float*)(ws + WS_VPART);                   // zero vpart + cpart (contiguous)
  for (int i = tid; i < (VSPLIT + HSPLIT) * NSEG; i += stride) vz[i] = 0.0f;
}

__global__ void prep2_kernel(char* __restrict__ ws) {    // finalize c1/c2
  int n = threadIdx.x;
  float a1 = 0.f, a2 = 0.f, b1 = 0.f, b2 = 0.f;
  #pragma unroll
  for (int j = 0; j < 8; j++) {
    a1 += ((const float*)(ws + WS_C1A))[j*256 + n];
    a2 += ((const float*)(ws + WS_C2A))[j*256 + n];
    b1 += ((const float*)(ws + WS_C1B))[j*256 + n];
    b2 += ((const float*)(ws + WS_C2B))[j*256 + n];
  }
  ((float*)(ws + WS_C1AF))[n] = a1;
  ((float*)(ws + WS_C2AF))[n] = a2;
  ((float*)(ws + WS_C1BF))[n] = b1;
  ((float*)(ws + WS_C2BF))[n] = b2;
}

__global__ void hist_kernel(const int* __restrict__ bidx, int N, float* __restrict__ cpart) {
  int tid = blockIdx.x * blockDim.x + threadIdx.x;
  int stride = gridDim.x * blockDim.x;
  for (int i = tid; i < N; i += stride)
    atomicAdd(&cpart[(i & (HSPLIT-1))*NSEG + bidx[i]], 1.0f);
}

// k1: GEMM1 + LN stats + h(bf16) out. One wave = 16 rows x 256 cols. No LDS, no barriers.
__global__ __launch_bounds__(256, 2) void k1_kernel(
    const float* __restrict__ feats, const float* __restrict__ meanp,
    const float* __restrict__ invp, const float* __restrict__ biasp,
    const short* __restrict__ weT, short* __restrict__ hc, floatx2* __restrict__ rsmu,
    int kstride, int ksteps, int f, int nG16)
{
  const int wave = threadIdx.x >> 6;
  const int lane = threadIdx.x & 63;
  const int l15  = lane & 15;
  const int quad = lane >> 4;

  float b1v[16];
  #pragma unroll
  for (int nt = 0; nt < 16; nt++) b1v[nt] = biasp[16*nt + l15];

  const int wstride = gridDim.x * 4;
  for (int g = blockIdx.x * 4 + wave; g < nG16; g += wstride) {
    const int m0 = g * 16;
    floatx4 acc[16];
    #pragma unroll
    for (int nt = 0; nt < 16; nt++) acc[nt] = 0.0f;

    for (int kk = 0; kk < ksteps; kk++) {
      const int k0 = kk*32 + quad*8;
      short8 a = {0,0,0,0,0,0,0,0};
      if (k0 < f) {
        floatx4 mv0 = *(const floatx4*)(meanp + k0);
        floatx4 mv1 = *(const floatx4*)(meanp + k0 + 4);
        floatx4 iv0 = *(const floatx4*)(invp + k0);
        floatx4 iv1 = *(const floatx4*)(invp + k0 + 4);
        const float* fp = feats + (size_t)(m0 + l15) * f + k0;
        floatx4 x0 = *(const floatx4*)fp;
        floatx4 x1 = *(const floatx4*)(fp + 4);
        #pragma unroll
        for (int e = 0; e < 4; e++) {
          float h0 = (x0[e] - mv0[e]) * iv0[e];
          h0 = fminf(fmaxf(h0, -5.0f), 5.0f);
          a[e] = f2bf(h0);
          float h1 = (x1[e] - mv1[e]) * iv1[e];
          h1 = fminf(fmaxf(h1, -5.0f), 5.0f);
          a[4+e] = f2bf(h1);
        }
      }
      #pragma unroll
      for (int nt = 0; nt < 16; nt++) {
        short8 bw = *(const short8*)(weT + (size_t)(16*nt + l15) * kstride + kk*32 + quad*8);
        acc[nt] = __builtin_amdgcn_mfma_f32_16x16x32_bf16(a, bw, acc[nt], 0, 0, 0);
      }
    }

    // epilogue: relu(.+b1) -> h (trunc bf16), stats in regs
    float s4[4] = {0,0,0,0}, s24[4] = {0,0,0,0};
    short* hrow = hc + (size_t)(m0 + 4*quad) * 256 + l15;
    #pragma unroll
    for (int nt = 0; nt < 16; nt++) {
      float bb = b1v[nt];
      #pragma unroll
      for (int r = 0; r < 4; r++) {
        float h = fmaxf(acc[nt][r] + bb, 0.0f);
        s4[r] += h;
        s24[r] = fmaf(h, h, s24[r]);
        hrow[r*256 + 16*nt] = f2bf_tr(h);
      }
    }
    #pragma unroll
    for (int r = 0; r < 4; r++) {
      float s = s4[r], s2 = s24[r];
      s  += __shfl_xor(s, 1, 64);  s2 += __shfl_xor(s2, 1, 64);
      s  += __shfl_xor(s, 2, 64);  s2 += __shfl_xor(s2, 2, 64);
      s  += __shfl_xor(s, 4, 64);  s2 += __shfl_xor(s2, 4, 64);
      s  += __shfl_xor(s, 8, 64);  s2 += __shfl_xor(s2, 8, 64);
      if (l15 == 0) {
        float mu  = s * (1.0f/256.0f);
        float var = fmaxf(s2 * (1.0f/256.0f) - mu*mu, 0.0f);
        float rs  = rsqrtf(var + 1e-5f);
        floatx2 v; v[0] = mu * rs; v[1] = rs;
        rsmu[m0 + 4*quad + r] = v;
      }
    }
  }
}

// k2: GEMM2 + value dot + scatter. B-frags in regs; h staged 64-row tiles via LDS.
__global__ __launch_bounds__(256, 2) void k2_kernel(
    const short* __restrict__ hc, const floatx2* __restrict__ rsmu,
    const short* __restrict__ w2gT, const float* __restrict__ c1p,
    const float* __restrict__ c2p, const float* __restrict__ Wv,
    const int* __restrict__ bidx, int bidxOff, int nG16, int nTiles,
    float* __restrict__ vpart)
{
  __shared__ __attribute__((aligned(16))) short zt[64*264];

  const int tid  = threadIdx.x;
  const int wave = tid >> 6;
  const int lane = tid & 63;
  const int l15  = lane & 15;
  const int quad = lane >> 4;

  // B-frags resident: 8kk x 4nt
  short8 bw[8][4];
  #pragma unroll
  for (int kk = 0; kk < 8; kk++)
    #pragma unroll
    for (int nt = 0; nt < 4; nt++)
      bw[kk][nt] = *(const short8*)(w2gT + (size_t)(64*wave + 16*nt + l15)*256 + kk*32 + quad*8);

  float c1v[4], c2v[4], wvv[4];
  #pragma unroll
  for (int nt = 0; nt < 4; nt++) {
    int col = 64*wave + 16*nt + l15;
    c1v[nt] = c1p[col];  c2v[nt] = c2p[col];  wvv[nt] = Wv[col];
  }

  const int srow = tid >> 2, scs = tid & 3;   // stage mapping: 4 threads/row
  const int split = (blockIdx.x & (VSPLIT-1)) * NSEG;

  for (int tile = blockIdx.x; tile < nTiles; tile += gridDim.x) {
    const int m0 = tile * 64;
    // stage 64x256 bf16 tile -> LDS (stride 264)
    {
      const short* src = hc + (size_t)(m0 + srow) * 256 + 64*scs;
      short* dst = zt + srow*264 + 64*scs;
      #pragma unroll
      for (int j = 0; j < 8; j++)
        *(floatx4*)(dst + 8*j) = *(const floatx4*)(src + 8*j);
    }
    __syncthreads();

    #pragma unroll
    for (int sub = 0; sub < 4; sub++) {
      int g16 = tile*4 + sub;
      if (g16 < nG16) {
        const int ms = sub*16;
        floatx4 acc[4];
        #pragma unroll
        for (int nt = 0; nt < 4; nt++) acc[nt] = 0.0f;
        #pragma unroll
        for (int kk = 0; kk < 8; kk++) {
          short8 a = *(const short8*)(zt + (ms + l15)*264 + kk*32 + quad*8);
          #pragma unroll
          for (int nt = 0; nt < 4; nt++)
            acc[nt] = __builtin_amdgcn_mfma_f32_16x16x32_bf16(a, bw[kk][nt], acc[nt], 0, 0, 0);
        }
        // epilogue: y = relu(rs*q - mrs*c1 + c2); pv = y.Wv; reduce 16 lanes; atomic
        #pragma unroll
        for (int r = 0; r < 4; r++) {
          int row = m0 + ms + 4*quad + r;
          floatx2 rm = rsmu[row];
          float pv = 0.0f;
          #pragma unroll
          for (int nt = 0; nt < 4; nt++) {
            float t = fmaf(-rm[0], c1v[nt], c2v[nt]);
            float y = fmaf(rm[1], acc[nt][r], t);
            y = fmaxf(y, 0.0f);
            pv = fmaf(y, wvv[nt], pv);
          }
          pv += __shfl_xor(pv, 1, 64);
          pv += __shfl_xor(pv, 2, 64);
          pv += __shfl_xor(pv, 4, 64);
          pv += __shfl_xor(pv, 8, 64);
          if (l15 == 0) {
            int seg = bidx[bidxOff + row];
            atomicAdd(&vpart[split + seg], pv);
          }
        }
      }
    }
    __syncthreads();
  }
}

__global__ void final_kernel(const float* __restrict__ vpart, const float* __restrict__ cpart,
                             const float* __restrict__ bv, float* __restrict__ out, int nseg) {
  int s = blockIdx.x * blockDim.x + threadIdx.x;
  if (s < nseg) {
    float a = 0.0f, c = 0.0f;
    #pragma unroll 8
    for (int i = 0; i < VSPLIT; i++) a += vpart[i*NSEG + s];
    #pragma unroll
    for (int i = 0; i < HSPLIT; i++) c += cpart[i*NSEG + s];
    out[s] = a / fmaxf(c, 1.0f) + bv[0];
  }
}

extern "C" void kernel_launch(void* const* d_in, const int* in_sizes, int n_in,
                              void* d_out, int out_size, void* d_ws, size_t ws_size,
                              hipStream_t stream) {
  const float* featsA = (const float*)d_in[0];
  const float* featsB = (const float*)d_in[1];
  const float* mA     = (const float*)d_in[2];
  const float* sA     = (const float*)d_in[3];
  const float* mB     = (const float*)d_in[4];
  const float* sB     = (const float*)d_in[5];
  const float* WA     = (const float*)d_in[6];
  const float* bA     = (const float*)d_in[7];
  const float* gA     = (const float*)d_in[8];
  const float* betaA  = (const float*)d_in[9];
  const float* WB     = (const float*)d_in[10];
  const float* bB     = (const float*)d_in[11];
  const float* gB     = (const float*)d_in[12];
  const float* betaB  = (const float*)d_in[13];
  const float* Wback  = (const float*)d_in[14];
  const float* bback  = (const float*)d_in[15];
  const float* Wv     = (const float*)d_in[16];
  const float* bv     = (const float*)d_in[17];
  const int*   bidx   = (const int*)d_in[18];

  const int nA = in_sizes[0] / 32;
  const int nB = in_sizes[1] / 48;
  char* ws = (char*)d_ws;
  short*   hc    = (short*)(ws + WS_H);
  floatx2* rsmu  = (floatx2*)(ws + WS_RSMU);
  float*   vpart = (float*)(ws + WS_VPART);
  float*   cpart = (float*)(ws + WS_CPART);
  float*   out   = (float*)d_out;

  prep_kernel<<<256, 256, 0, stream>>>(WA, WB, Wback, gA, betaA, gB, betaB,
                                       bback, sA, sB, ws);
  prep2_kernel<<<1, 256, 0, stream>>>(ws);
  hist_kernel<<<512, 256, 0, stream>>>(bidx, nA + nB, cpart);

  for (int type = 0; type < 2; type++) {
    const int   n      = type == 0 ? nA : nB;
    const float* feats = type == 0 ? featsA : featsB;
    const float* meanp = type == 0 ? mA : mB;
    const float* invp  = (const float*)(ws + (type == 0 ? WS_INVA : WS_INVB));
    const float* biasp = type == 0 ? bA : bB;
    const short* weT   = (const short*)(ws + (type == 0 ? WS_WAT : WS_WBT2));
    const short* w2gT  = (const short*)(ws + (type == 0 ? WS_W2GA : WS_W2GB));
    const float* c1p   = (const float*)(ws + (type == 0 ? WS_C1AF : WS_C1BF));
    const float* c2p   = (const float*)(ws + (type == 0 ? WS_C2AF : WS_C2BF));
    const int kstride  = type == 0 ? 32 : 64;
    const int ksteps   = type == 0 ? 1 : 2;
    const int f        = type == 0 ? 32 : 48;
    const int bidxBase = type == 0 ? 0 : nA;

    for (int off = 0; off < n; off += CHUNK) {
      const int rows  = min(CHUNK, n - off);
      const int nG16  = rows / 16;            // nA, nB, CHUNK all %16 == 0
      const int nTile = (nG16 + 3) / 4;
      k1_kernel<<<512, 256, 0, stream>>>(feats + (size_t)off * f, meanp, invp, biasp,
                                         weT, hc, rsmu, kstride, ksteps, f, nG16);
      k2_kernel<<<512, 256, 0, stream>>>(hc, rsmu, w2gT, c1p, c2p, Wv, bidx,
                                         bidxBase + off, nG16, nTile, vpart);
    }
  }

  final_kernel<<<2, 256, 0, stream>>>(vpart, cpart, bv, out, out_size);
}

// Round 8
// 408.425 us; speedup vs baseline: 1.3863x; 1.3863x over previous
//
#include <hip/hip_runtime.h>

#define NSEG 512
#define VSPLIT 32
#define HSPLIT 16

typedef __attribute__((ext_vector_type(8))) short short8;
typedef __attribute__((ext_vector_type(4))) float floatx4;
typedef __attribute__((ext_vector_type(2))) unsigned uint2v;

// ws layout (bytes), all 16B-aligned
#define WS_WETA  0        // short[256][64]  [n][k]: WA^T, bias row at k=32, zero pad
#define WS_WETB  32768    // short[256][64]  [n][k]: WB^T, bias row at k=48, zero pad
#define WS_W2GA  65536    // short[256][256] (gA*Wback)^T
#define WS_W2GB  196608   // short[256][256] (gB*Wback)^T
#define WS_C1A   327680   // float[8][256] partials
#define WS_C2A   335872
#define WS_C1B   344064
#define WS_C2B   352256
#define WS_C1AF  360448   // float[256] finals
#define WS_C2AF  361472
#define WS_C1BF  362496
#define WS_C2BF  363520
#define WS_INVA  364544   // float[32]
#define WS_INVB  364672   // float[48]
#define WS_VPART 364864   // float[VSPLIT][NSEG]
#define WS_CPART 430400   // float[HSPLIT][NSEG]
// end 463168

__device__ __forceinline__ short f2bf(float f) {  // RNE
  unsigned u = __builtin_bit_cast(unsigned, f);
  u += 0x7FFFu + ((u >> 16) & 1u);
  return (short)(u >> 16);
}

__global__ void prep_kernel(const float* __restrict__ WA, const float* __restrict__ WB,
                            const float* __restrict__ Wback,
                            const float* __restrict__ gA, const float* __restrict__ betaA,
                            const float* __restrict__ gB, const float* __restrict__ betaB,
                            const float* __restrict__ bback,
                            const float* __restrict__ sA, const float* __restrict__ sB,
                            const float* __restrict__ bA, const float* __restrict__ bB,
                            char* __restrict__ ws) {
  short* weTA = (short*)(ws + WS_WETA);
  short* weTB = (short*)(ws + WS_WETB);
  short* w2gA = (short*)(ws + WS_W2GA);
  short* w2gB = (short*)(ws + WS_W2GB);
  int tid = blockIdx.x * blockDim.x + threadIdx.x;
  int stride = gridDim.x * blockDim.x;
  for (int i = tid; i < 256*64; i += stride) {   // [n][k] with bias row at k=f
    int n = i >> 6, k = i & 63;
    weTA[i] = (k < 32) ? f2bf(WA[k*256 + n]) : (k == 32 ? f2bf(bA[n]) : (short)0);
    weTB[i] = (k < 48) ? f2bf(WB[k*256 + n]) : (k == 48 ? f2bf(bB[n]) : (short)0);
  }
  for (int i = tid; i < 256*256; i += stride) {  // (g*Wback)[k][n] -> [n][k]
    int k = i >> 8, n = i & 255;
    float w = Wback[i];
    w2gA[n*256 + k] = f2bf(gA[k] * w);
    w2gB[n*256 + k] = f2bf(gB[k] * w);
  }
  if (blockIdx.x < 8) {                          // c1/c2 partials, no atomics
    int kc = blockIdx.x, n = threadIdx.x;
    float a1 = 0.f, a2 = 0.f, b1 = 0.f, b2 = 0.f;
    for (int k = kc*32; k < kc*32 + 32; k++) {
      float w = Wback[k*256 + n];
      a1 += gA[k] * w;  a2 += betaA[k] * w;
      b1 += gB[k] * w;  b2 += betaB[k] * w;
    }
    float bb = (kc == 0) ? bback[n] : 0.0f;
    ((float*)(ws + WS_C1A))[kc*256 + n] = a1;
    ((float*)(ws + WS_C2A))[kc*256 + n] = a2 + bb;
    ((float*)(ws + WS_C1B))[kc*256 + n] = b1;
    ((float*)(ws + WS_C2B))[kc*256 + n] = b2 + bb;
  }
  if (tid < 32) ((float*)(ws + WS_INVA))[tid] = 1.0f / sA[tid];
  if (tid < 48) ((float*)(ws + WS_INVB))[tid] = 1.0f / sB[tid];
  float* vz = (float*)(ws + WS_VPART);
  for (int i = tid; i < (VSPLIT + HSPLIT) * NSEG; i += stride) vz[i] = 0.0f;
}

__global__ void prep2_kernel(char* __restrict__ ws) {
  int n = threadIdx.x;
  float a1 = 0.f, a2 = 0.f, b1 = 0.f, b2 = 0.f;
  #pragma unroll
  for (int j = 0; j < 8; j++) {
    a1 += ((const float*)(ws + WS_C1A))[j*256 + n];
    a2 += ((const float*)(ws + WS_C2A))[j*256 + n];
    b1 += ((const float*)(ws + WS_C1B))[j*256 + n];
    b2 += ((const float*)(ws + WS_C2B))[j*256 + n];
  }
  ((float*)(ws + WS_C1AF))[n] = a1;
  ((float*)(ws + WS_C2AF))[n] = a2;
  ((float*)(ws + WS_C1BF))[n] = b1;
  ((float*)(ws + WS_C2BF))[n] = b2;
}

__global__ void hist_kernel(const int* __restrict__ bidx, int N, float* __restrict__ cpart) {
  int tid = blockIdx.x * blockDim.x + threadIdx.x;
  int stride = gridDim.x * blockDim.x;
  for (int i = tid; i < N; i += stride)
    atomicAdd(&cpart[(i & (HSPLIT-1))*NSEG + bidx[i]], 1.0f);
}

__global__ __launch_bounds__(256, 2) void fused_kernel(
    const float* __restrict__ featsA, const float* __restrict__ featsB,
    const float* __restrict__ mA, const float* __restrict__ mB,
    const float* __restrict__ Wv, const int* __restrict__ bidx,
    const char* __restrict__ ws, float* __restrict__ vpart,
    int tilesA, int nA, int nB)
{
  __shared__ __attribute__((aligned(16))) short ztile[64*264];  // h [row][col]
  __shared__ __attribute__((aligned(16))) float rsmu_s[64][2];
  __shared__ __attribute__((aligned(16))) float vpw[64][4];

  const int tid  = threadIdx.x;
  const int wave = tid >> 6;
  const int lane = tid & 63;
  const int l15  = lane & 15;
  const int quad = lane >> 4;

  const bool isA = (blockIdx.x < (unsigned)tilesA);
  const int  tb  = isA ? blockIdx.x : (blockIdx.x - tilesA);
  const int  r0  = tb * 64;
  const int  nrows = isA ? nA : nB;
  const int  valid = min(64, nrows - r0);
  const float* feats = isA ? featsA : featsB;
  const float* meanp = isA ? mA : mB;
  const float* invp  = (const float*)(ws + (isA ? WS_INVA : WS_INVB));
  const short* weT   = (const short*)(ws + (isA ? WS_WETA : WS_WETB));
  const short* w2gT  = (const short*)(ws + (isA ? WS_W2GA : WS_W2GB));
  const float* c1p   = (const float*)(ws + (isA ? WS_C1AF : WS_C1BF));
  const float* c2p   = (const float*)(ws + (isA ? WS_C2AF : WS_C2BF));
  const int f = isA ? 32 : 48;

  // per-wave epilogue2 constants (cols 64*wave + 16*nt + l15)
  float c1v[4], c2v[4], wvv[4];
  #pragma unroll
  for (int nt = 0; nt < 4; nt++) {
    int col = 64*wave + 16*nt + l15;
    c1v[nt] = c1p[col];  c2v[nt] = c2p[col];  wvv[nt] = Wv[col];
  }

  // ---- GEMM1 (transposed): h^T = W1^T @ featsN^T. Wave owns rows 16w..16w+15, all 256 cols.
  // A-frag: weT[n=16mt+l15][k], B-frag: featsN[row=l15][k]. Bias folded as K-row (k==f, feats=1).
  const int grow = r0 + 16*wave + l15;          // this lane's feats row
  const bool rv  = grow < nrows;

  short8 wf[2][16];
  #pragma unroll
  for (int ks = 0; ks < 2; ks++)
    #pragma unroll
    for (int mt = 0; mt < 16; mt++)
      wf[ks][mt] = *(const short8*)(weT + (16*mt + l15)*64 + ks*32 + quad*8);

  floatx4 acc1[16];
  #pragma unroll
  for (int mt = 0; mt < 16; mt++) acc1[mt] = 0.0f;

  #pragma unroll
  for (int ks = 0; ks < 2; ks++) {
    const int k0 = ks*32 + quad*8;
    short8 b = {0,0,0,0,0,0,0,0};
    if (k0 + 8 <= f) {
      if (rv) {
        floatx4 mv0 = *(const floatx4*)(meanp + k0);
        floatx4 mv1 = *(const floatx4*)(meanp + k0 + 4);
        floatx4 iv0 = *(const floatx4*)(invp + k0);
        floatx4 iv1 = *(const floatx4*)(invp + k0 + 4);
        const float* fp = feats + (size_t)grow * f + k0;
        floatx4 x0 = *(const floatx4*)fp;
        floatx4 x1 = *(const floatx4*)(fp + 4);
        #pragma unroll
        for (int e = 0; e < 4; e++) {
          float h0 = (x0[e] - mv0[e]) * iv0[e];
          h0 = fminf(fmaxf(h0, -5.0f), 5.0f);
          b[e] = f2bf(h0);
          float h1 = (x1[e] - mv1[e]) * iv1[e];
          h1 = fminf(fmaxf(h1, -5.0f), 5.0f);
          b[4+e] = f2bf(h1);
        }
      }
    } else if (k0 == f) {
      if (rv) b[0] = (short)0x3F80;   // bf16(1.0) -> multiplies bias row
    }
    #pragma unroll
    for (int mt = 0; mt < 16; mt++)
      acc1[mt] = __builtin_amdgcn_mfma_f32_16x16x32_bf16(wf[ks][mt], b, acc1[mt], 0, 0, 0);
  }

  // ---- epilogue1: relu -> packed bf16 ds_write_b64; lane-local LN stats ----
  {
    float s = 0.0f, s2 = 0.0f;
    short* zrow = ztile + (16*wave + l15)*264;   // C col = l15 = this lane's row
    #pragma unroll
    for (int mt = 0; mt < 16; mt++) {
      float hv[4];
      #pragma unroll
      for (int r = 0; r < 4; r++) {
        float h = fmaxf(acc1[mt][r], 0.0f);      // bias already in acc via K-row
        s += h;
        s2 = fmaf(h, h, s2);
        hv[r] = h;
      }
      unsigned p01 = __builtin_amdgcn_perm(__builtin_bit_cast(unsigned, hv[1]),
                                           __builtin_bit_cast(unsigned, hv[0]), 0x07060302u);
      unsigned p23 = __builtin_amdgcn_perm(__builtin_bit_cast(unsigned, hv[3]),
                                           __builtin_bit_cast(unsigned, hv[2]), 0x07060302u);
      uint2v pk; pk[0] = p01; pk[1] = p23;
      *(uint2v*)(zrow + 16*mt + 4*quad) = pk;    // cols n = 16mt+4q..+3
    }
    // reduce across quads (each quad holds a quarter of the 256 cols for row l15)
    s  += __shfl_xor(s, 16, 64);  s2 += __shfl_xor(s2, 16, 64);
    s  += __shfl_xor(s, 32, 64);  s2 += __shfl_xor(s2, 32, 64);
    float mu  = s * (1.0f/256.0f);
    float var = fmaxf(s2 * (1.0f/256.0f) - mu*mu, 0.0f);
    float rs  = rsqrtf(var + 1e-5f);
    if (lane < 16) {                             // quad 0 writes row scalars
      rsmu_s[16*wave + l15][0] = mu * rs;
      rsmu_s[16*wave + l15][1] = rs;
    }
  }
  __syncthreads();
  __builtin_amdgcn_sched_barrier(0);             // keep GEMM2 loads below (reg phases)

  // ---- GEMM2: q = h @ (g*Wback). Wave owns cols 64w..64w+63, all 64 rows. B upfront. ----
  short8 bw[8][4];
  #pragma unroll
  for (int kk = 0; kk < 8; kk++)
    #pragma unroll
    for (int nt = 0; nt < 4; nt++)
      bw[kk][nt] = *(const short8*)(w2gT + (size_t)(64*wave + 16*nt + l15)*256 + kk*32 + quad*8);

  floatx4 acc2[4][4];
  #pragma unroll
  for (int mt = 0; mt < 4; mt++)
    #pragma unroll
    for (int nt = 0; nt < 4; nt++)
      acc2[mt][nt] = 0.0f;

  #pragma unroll
  for (int kk = 0; kk < 8; kk++) {
    short8 a[4];
    #pragma unroll
    for (int mt = 0; mt < 4; mt++)
      a[mt] = *(const short8*)(ztile + (16*mt + l15)*264 + kk*32 + quad*8);
    #pragma unroll
    for (int mt = 0; mt < 4; mt++)
      #pragma unroll
      for (int nt = 0; nt < 4; nt++)
        acc2[mt][nt] = __builtin_amdgcn_mfma_f32_16x16x32_bf16(a[mt], bw[kk][nt], acc2[mt][nt], 0, 0, 0);
  }

  // ---- epilogue2: y = relu(rs*q - mrs*c1 + c2); pv = y.Wv; one value per row ----
  #pragma unroll
  for (int mt = 0; mt < 4; mt++)
    #pragma unroll
    for (int r = 0; r < 4; r++) {
      int rr = 16*mt + 4*quad + r;
      float mrs = rsmu_s[rr][0], rs = rsmu_s[rr][1];
      float pv = 0.0f;
      #pragma unroll
      for (int nt = 0; nt < 4; nt++) {
        float t = fmaf(-mrs, c1v[nt], c2v[nt]);
        float y = fmaf(rs, acc2[mt][nt][r], t);
        y = fmaxf(y, 0.0f);
        pv = fmaf(y, wvv[nt], pv);
      }
      pv += __shfl_xor(pv, 1, 64);
      pv += __shfl_xor(pv, 2, 64);
      pv += __shfl_xor(pv, 4, 64);
      pv += __shfl_xor(pv, 8, 64);
      if (l15 == 0) vpw[rr][wave] = pv;
    }
  __syncthreads();

  if (tid < valid) {
    floatx4 vv = *(const floatx4*)vpw[tid];
    float v = vv[0] + vv[1] + vv[2] + vv[3];
    int g = (isA ? r0 : (nA + r0)) + tid;
    int seg = bidx[g];
    int split = blockIdx.x & (VSPLIT - 1);
    atomicAdd(&vpart[split*NSEG + seg], v);
  }
}

__global__ void final_kernel(const float* __restrict__ vpart, const float* __restrict__ cpart,
                             const float* __restrict__ bv, float* __restrict__ out, int nseg) {
  int s = blockIdx.x * blockDim.x + threadIdx.x;
  if (s < nseg) {
    float a = 0.0f, c = 0.0f;
    #pragma unroll 8
    for (int i = 0; i < VSPLIT; i++) a += vpart[i*NSEG + s];
    #pragma unroll
    for (int i = 0; i < HSPLIT; i++) c += cpart[i*NSEG + s];
    out[s] = a / fmaxf(c, 1.0f) + bv[0];
  }
}

extern "C" void kernel_launch(void* const* d_in, const int* in_sizes, int n_in,
                              void* d_out, int out_size, void* d_ws, size_t ws_size,
                              hipStream_t stream) {
  const float* featsA = (const float*)d_in[0];
  const float* featsB = (const float*)d_in[1];
  const float* mA     = (const float*)d_in[2];
  const float* sA     = (const float*)d_in[3];
  const float* mB     = (const float*)d_in[4];
  const float* sB     = (const float*)d_in[5];
  const float* WA     = (const float*)d_in[6];
  const float* bA     = (const float*)d_in[7];
  const float* gA     = (const float*)d_in[8];
  const float* betaA  = (const float*)d_in[9];
  const float* WB     = (const float*)d_in[10];
  const float* bB     = (const float*)d_in[11];
  const float* gB     = (const float*)d_in[12];
  const float* betaB  = (const float*)d_in[13];
  const float* Wback  = (const float*)d_in[14];
  const float* bback  = (const float*)d_in[15];
  const float* Wv     = (const float*)d_in[16];
  const float* bv     = (const float*)d_in[17];
  const int*   bidx   = (const int*)d_in[18];

  const int nA = in_sizes[0] / 32;
  const int nB = in_sizes[1] / 48;
  char* ws = (char*)d_ws;
  float* vpart = (float*)(ws + WS_VPART);
  float* cpart = (float*)(ws + WS_CPART);
  float* out   = (float*)d_out;

  prep_kernel<<<256, 256, 0, stream>>>(WA, WB, Wback, gA, betaA, gB, betaB,
                                       bback, sA, sB, bA, bB, ws);
  prep2_kernel<<<1, 256, 0, stream>>>(ws);
  hist_kernel<<<512, 256, 0, stream>>>(bidx, nA + nB, cpart);

  const int tilesA = (nA + 63) / 64;
  const int tilesB = (nB + 63) / 64;
  fused_kernel<<<tilesA + tilesB, 256, 0, stream>>>(
      featsA, featsB, mA, mB, Wv, bidx, ws, vpart, tilesA, nA, nB);

  final_kernel<<<2, 256, 0, stream>>>(vpart, cpart, bv, out, out_size);
}